// Round 4
// baseline (248.965 us; speedup 1.0000x reference)
//
#include <hip/hip_runtime.h>

// HexagonalSensor photon binning: 16.7M photons -> 1801 hex pixels.
// R4: replace atomicAdd(float*) on LDS (CAS-loop lowering suspected: 105us
// invariant to occupancy/VALU changes, all pipes <15% busy) with
// unsafeAtomicAdd -> hardware ds_add_f32 (non-return, fire-and-forget).
// Also 2-deep load pipeline (6 float4 loads in flight per thread).

#define NPIX   1801      // 3*R*(R+1)+1 for R=24
#define LUTQ   49
#define LUTR   49
#define LUTN   (LUTQ * LUTR)
#define TPB    256
#define NBLK   2048      // 8 blocks/CU * 256 CUs
#define GROUPS 32        // reduction groups -> 32 atomics per pixel

__device__ __forceinline__ void hist_add(float* addr, float v) {
    // unsafeAtomicAdd emits HW fp atomic (ds_add_f32 for LDS pointers),
    // bypassing the CAS-loop lowering of plain atomicAdd(float*).
    unsafeAtomicAdd(addr, v);
}

__global__ __launch_bounds__(TPB) void hex_hist_kernel(
    const float* __restrict__ gx, const float* __restrict__ gy,
    const float* __restrict__ gv, const int* __restrict__ glut,
    const float* __restrict__ p_hs, const float* __restrict__ p_rot,
    const float* __restrict__ p_ox, const float* __restrict__ p_oy,
    const int* __restrict__ p_qmin, const int* __restrict__ p_rmin,
    const int* __restrict__ p_np,
    float* __restrict__ partials, float* __restrict__ out, int n)
{
    __shared__ float hist[NPIX];
    __shared__ int   lut[LUTN];

    const int tid = threadIdx.x;

    for (int i = tid; i < NPIX; i += TPB) hist[i] = 0.0f;
    for (int i = tid; i < LUTN; i += TPB) lut[i] = glut[i];
    if (blockIdx.x == 0) {
        const int np = p_np[0];
        for (int i = tid; i < np; i += TPB) out[i] = 0.0f;
    }
    __syncthreads();

    // fold rotation + offset + axial transform into one 2x2 affine map:
    // q = Aq*x + Bq*y + Cq ; r = Ar*x + Br*y + Cr   (no divides in loop)
    const float hs   = p_hs[0];
    const float rot  = p_rot[0];
    const float ox   = p_ox[0];
    const float oy   = p_oy[0];
    const int   qmin = p_qmin[0];
    const int   rmin = p_rmin[0];

    const float ca = cosf(-rot);
    const float sa = sinf(-rot);
    const float k1 = sqrtf(3.0f) / 3.0f;
    const float inv_hs = 1.0f / hs;
    const float Aq = (k1 * ca - sa * (1.0f / 3.0f)) * inv_hs;
    const float Bq = (-k1 * sa - ca * (1.0f / 3.0f)) * inv_hs;
    const float Ar = ((2.0f / 3.0f) * sa) * inv_hs;
    const float Br = ((2.0f / 3.0f) * ca) * inv_hs;
    const float Cq = -(Aq * ox + Bq * oy);
    const float Cr = -(Ar * ox + Br * oy);

    auto bin_one = [&](float px, float py, float pv) {
        const float q = fmaf(Aq, px, fmaf(Bq, py, Cq));
        const float r = fmaf(Ar, px, fmaf(Br, py, Cr));
        const float s = -q - r;
        const float qr0 = rintf(q);   // v_rndne: round-half-even like jnp.round
        const float rr0 = rintf(r);
        const float sr0 = rintf(s);
        const float qd = fabsf(qr0 - q);
        const float rd = fabsf(rr0 - r);
        const float sd = fabsf(sr0 - s);
        const bool c1 = (qd > rd) && (qd > sd);
        const bool c2 = (rd > qd) && (rd > sd);
        const float qf = c1 ? (-rr0 - sr0) : qr0;
        const float rf = c2 ? (-qr0 - sr0) : rr0;
        const int qi = (int)qf - qmin;
        const int ri = (int)rf - rmin;
        if ((unsigned)qi < LUTQ && (unsigned)ri < LUTR) {
            const int p = lut[qi * LUTR + ri];
            if (p >= 0) hist_add(&hist[p], pv);   // ds_add_f32 non-return
        }
    };

    auto bin4 = [&](const float4& a, const float4& b, const float4& v) {
        bin_one(a.x, b.x, v.x);
        bin_one(a.y, b.y, v.y);
        bin_one(a.z, b.z, v.z);
        bin_one(a.w, b.w, v.w);
    };

    const int gthreads = gridDim.x * TPB;
    const int gtid     = blockIdx.x * TPB + tid;
    const int nvec     = n >> 2;

    const float4* x4 = (const float4*)gx;
    const float4* y4 = (const float4*)gy;
    const float4* v4 = (const float4*)gv;

    // 2-deep software pipeline: up to 6 float4 loads in flight per thread
    int i0 = gtid;
    if (i0 < nvec) {
        float4 a0 = x4[i0], b0 = y4[i0], v0 = v4[i0];
        int  i1 = i0 + gthreads;
        bool m1 = i1 < nvec;
        float4 a1, b1, v1;
        if (m1) { a1 = x4[i1]; b1 = y4[i1]; v1 = v4[i1]; }
        for (;;) {
            const int  i2 = i1 + gthreads;
            const bool m2 = m1 && (i2 < nvec);
            float4 a2, b2, v2;
            if (m2) { a2 = x4[i2]; b2 = y4[i2]; v2 = v4[i2]; }
            bin4(a0, b0, v0);
            if (!m1) break;
            a0 = a1; b0 = b1; v0 = v1;
            a1 = a2; b1 = b2; v1 = v2;
            m1 = m2; i1 = i2;
        }
    }
    for (int t = (nvec << 2) + gtid; t < n; t += gthreads)
        bin_one(gx[t], gy[t], gv[t]);

    __syncthreads();

    float* prow = partials + (size_t)blockIdx.x * NPIX;
    for (int p = tid; p < NPIX; p += TPB) prow[p] = hist[p];
}

__global__ __launch_bounds__(TPB) void hex_reduce_kernel(
    const float* __restrict__ partials, float* __restrict__ out,
    const int* __restrict__ p_np, int rows_per_group)
{
    const int np = p_np[0];
    const int p  = blockIdx.x * TPB + threadIdx.x;
    if (p >= np || p >= NPIX) return;
    const int row0 = blockIdx.y * rows_per_group;
    float sum = 0.0f;
    #pragma unroll 8
    for (int b = 0; b < rows_per_group; ++b)
        sum += partials[(size_t)(row0 + b) * NPIX + p];
    atomicAdd(&out[p], sum);
}

extern "C" void kernel_launch(void* const* d_in, const int* in_sizes, int n_in,
                              void* d_out, int out_size, void* d_ws, size_t ws_size,
                              hipStream_t stream) {
    const float* x      = (const float*)d_in[0];
    const float* y      = (const float*)d_in[1];
    const float* vals   = (const float*)d_in[2];
    const int*   lut    = (const int*)d_in[3];
    const float* hs     = (const float*)d_in[4];
    const float* rot    = (const float*)d_in[5];
    const float* offx   = (const float*)d_in[6];
    const float* offy   = (const float*)d_in[7];
    const int*   qmin   = (const int*)d_in[8];
    const int*   rmin   = (const int*)d_in[9];
    const int*   npix   = (const int*)d_in[10];
    float*       out    = (float*)d_out;
    float*       parts  = (float*)d_ws;
    const int    n      = in_sizes[0];

    int nblk = NBLK;
    const size_t row_bytes = (size_t)NPIX * sizeof(float);
    if (ws_size < (size_t)NBLK * row_bytes) {
        nblk = (int)(ws_size / row_bytes);
        nblk = (nblk / GROUPS) * GROUPS;
        if (nblk < GROUPS) nblk = GROUPS;
    }

    hipLaunchKernelGGL(hex_hist_kernel, dim3(nblk), dim3(TPB), 0, stream,
                       x, y, vals, lut, hs, rot, offx, offy, qmin, rmin, npix,
                       parts, out, n);

    const int rows_per_group = nblk / GROUPS;
    hipLaunchKernelGGL(hex_reduce_kernel,
                       dim3((NPIX + TPB - 1) / TPB, GROUPS), dim3(TPB), 0, stream,
                       parts, out, npix, rows_per_group);
}